// Round 15
// baseline (120.217 us; speedup 1.0000x reference)
//
#include <hip/hip_runtime.h>
#include <hip/hip_bf16.h>

#define NBOX  380
#define NLOCS 85
#define NINST 340   // B(4) * NLOCS(85)
#define SMB   6368  // per-batch LDS stride (floats)
#define W5T   12736 // W5 transposed stage offset (floats)

// box index -> location index (from _recon_indices structure)
__device__ __forceinline__ int loc_of_box(int n) {
    if (n < 256) return n >> 2;               // fm=8, 4 boxes/loc
    if (n < 352) return 64 + (n - 256) / 6;   // fm=4, 6 boxes/loc
    if (n < 376) return 80 + (n - 352) / 6;   // fm=2, 6 boxes/loc
    return 84;                                // fm=1, 4 boxes/loc
}

__device__ __forceinline__ float f4e(const float4& v, int kk) {
    return (kk == 0) ? v.x : (kk == 1) ? v.y : (kk == 2) ? v.z : v.w;
}

// Per-batch softmax over depths + per-box affine params + rect + compaction.
__device__ void box_params_dev(int b, const float* __restrict__ zwhere,
    const int* __restrict__ zpresent, const float* __restrict__ zdepth,
    float* wgt, float* sxs, float* oxs, float* sys, float* oys,
    int* binst, int* rect, int* cidx, int* cnt, float* sm)
{
    float* sd  = sm;         // 384 (380 used)
    float* red = sm + 384;   // 512
    const int tid = threadIdx.x;

    if (tid < NBOX) {
        int loc = loc_of_box(tid);
        sd[tid] = (zpresent[b * NBOX + tid] == 1) ? zdepth[b * NLOCS + loc] : -1000.0f;
    }
    __syncthreads();

    float m = (tid < NBOX) ? sd[tid] : -1e30f;
    red[tid] = m; __syncthreads();
    for (int s = 256; s > 0; s >>= 1) {
        if (tid < s) red[tid] = fmaxf(red[tid], red[tid + s]);
        __syncthreads();
    }
    m = red[0]; __syncthreads();

    float sum = (tid < NBOX) ? expf(sd[tid] - m) : 0.f;
    red[tid] = sum; __syncthreads();
    for (int s = 256; s > 0; s >>= 1) {
        if (tid < s) red[tid] += red[tid + s];
        __syncthreads();
    }
    float inv = 1.0f / red[0];
    __syncthreads();

    if (tid < NBOX) {
        int g = b * NBOX + tid;
        float wv = expf(sd[tid] - m) * inv;   // exp(-1000-m) underflows to exactly 0
        wgt[g] = wv;
        float cx = zwhere[g * 4 + 0], cy = zwhere[g * 4 + 1];
        float w  = zwhere[g * 4 + 2], h  = zwhere[g * 4 + 3];
        float isx = 1.0f / fmaxf(w, 1e-5f);
        float isy = 1.0f / fmaxf(h, 1e-5f);
        float sxv = isx * (63.0f / 127.0f);
        float oxv = 31.5f * (1.0f - 2.0f * cx * isx);
        float syv = isy * (63.0f / 127.0f);
        float oyv = 31.5f * (1.0f - 2.0f * cy * isy);
        sxs[g] = sxv; oxs[g] = oxv; sys[g] = syv; oys[g] = oyv;
        binst[g] = b * NLOCS + loc_of_box(tid);
        int wlo = min(127, max(0, (int)floorf((-1.0f - oxv) / sxv)));
        int whi = max(0, min(127, (int)ceilf((64.0f - oxv) / sxv)));
        int hlo = min(127, max(0, (int)floorf((-1.0f - oyv) / syv)));
        int hhi = max(0, min(127, (int)ceilf((64.0f - oyv) / syv)));
        rect[g] = wlo | (whi << 8) | (hlo << 16) | (hhi << 24);
        sd[tid] = wv;   // presence flag for compaction
    }
    __syncthreads();

    if (tid < 64) {   // wave 0: deterministic ascending compaction
        int base = 0;
        for (int c = 0; c < 6; ++c) {
            int n = c * 64 + tid;
            bool p = (n < NBOX) && (sd[n] > 0.0f);
            unsigned long long mask = __ballot(p);
            int pos = __popcll(mask & ((1ull << tid) - 1ull));
            if (p) cidx[b * NBOX + base + pos] = n;
            base += __popcll(mask);
        }
        if (tid == 0) cnt[b] = base;
    }
}

// Decoder: ONE (loc, batch-pair, row-half) per block, 512 threads.
// Co-tile-4 weights (float4 loads): x b128 feeds 16-32 FMAs (LDS-pipe relief).
// R13 post-mortem fixes: (a) W5 staged TRANSPOSED in LDS, not 48 registers
// held across the chunk loop (that spilled: VGPR=128 cap, +24MB scratch);
// (b) all LDS strides padded !=0 mod 32 banks AND float4-aligned
// (aL1 132, aL2 68, aL3 36, aL4 20) -- R13's stride-32 aL3 was a bank-aligned
// conflict (2.28M); (c) L3 chunked (2 rows/chunk from aL2 row c) to shrink
// live LDS and register sets.
// out[(2i+di, 2j+dj)][co] = act( b[co] + sum_k x[i,j][k] * W[3-(2di+dj)][k][co] )
// Per-batch LDS (floats, +q*SMB): s_x 0 | aL0 64 | aL1 576 (stride 132) |
//   aL2 1632 (stride 68) | aL3c overlay 0 (32px * 36) | aL4 3808 (128px * 20).
// W5t shared at 12736 (192). Total 12928 floats = 51,712 B -> 2+ blocks/CU.
__global__ __launch_bounds__(512, 2) void decode_fused_k(
    const float* __restrict__ z_what,
    const float* __restrict__ W0, const float* __restrict__ B0,
    const float* __restrict__ W1, const float* __restrict__ B1,
    const float* __restrict__ W2, const float* __restrict__ B2,
    const float* __restrict__ W3, const float* __restrict__ B3,
    const float* __restrict__ W4, const float* __restrict__ B4,
    const float* __restrict__ W5, const float* __restrict__ B5,
    const float* __restrict__ z_where, const int* __restrict__ z_present,
    const float* __restrict__ z_depth,
    float* __restrict__ wgt, float* __restrict__ sxs, float* __restrict__ oxs,
    float* __restrict__ sys, float* __restrict__ oys, int* __restrict__ binst,
    int* __restrict__ rect, int* __restrict__ cidx, int* __restrict__ cnt,
    float* __restrict__ dec)
{
    __shared__ __align__(16) float sm[12928];   // 51,712 B

    const int bid = blockIdx.x;
    if (bid >= NINST) {   // 4 trailing blocks: box params
        box_params_dev(bid - NINST, z_where, z_present, z_depth,
                       wgt, sxs, oxs, sys, oys, binst, rect, cidx, cnt, sm);
        return;
    }
    const int loc = bid % 85;
    const int r2g = bid / 85;                // 0..3
    const int bp = r2g & 1, s = r2g >> 1;    // batch-pair, row-half
    const int inst0 = (2 * bp + 0) * 85 + loc;
    const int inst1 = (2 * bp + 1) * 85 + loc;

    const int tid = threadIdx.x;

    if (tid < 128) {   // s_x for both batches
        int q = tid >> 6, l = tid & 63;
        sm[q * SMB + l] = z_what[(q ? inst1 : inst0) * 64 + l];
    }
    if (tid >= 128 && tid < 320) {   // W5t[ft][c][k] stage (192 floats)
        int idx = tid - 128;
        int ft = idx / 48, rem = idx % 48;
        int cc = rem >> 4, k = rem & 15;
        sm[W5T + idx] = W5[(ft * 16 + k) * 3 + cc];
    }
    __syncthreads();

    // ---- L0: K=64 -> 256ch, row s, cols 0..1. 128 threads: (j0, co4).
    if (tid < 128) {
        const int co4 = tid & 63, j0 = tid >> 6;
        const int ft = 3 - (2 * s + j0);
        const float* wp = W0 + (size_t)ft * 64 * 256 + co4 * 4;
        float aA[4] = {0.f,0.f,0.f,0.f}, aB[4] = {0.f,0.f,0.f,0.f};
        #pragma unroll 4
        for (int kq = 0; kq < 16; ++kq) {
            float4 xA = *(const float4*)&sm[kq * 4];
            float4 xB = *(const float4*)&sm[SMB + kq * 4];
            #pragma unroll
            for (int kk = 0; kk < 4; ++kk) {
                float4 w4 = *(const float4*)&wp[(kq * 4 + kk) * 256];
                float xa = f4e(xA, kk), xb = f4e(xB, kk);
                aA[0] = fmaf(xa, w4.x, aA[0]); aA[1] = fmaf(xa, w4.y, aA[1]);
                aA[2] = fmaf(xa, w4.z, aA[2]); aA[3] = fmaf(xa, w4.w, aA[3]);
                aB[0] = fmaf(xb, w4.x, aB[0]); aB[1] = fmaf(xb, w4.y, aB[1]);
                aB[2] = fmaf(xb, w4.z, aB[2]); aB[3] = fmaf(xb, w4.w, aB[3]);
            }
        }
        float4 b4 = *(const float4*)&B0[co4 * 4];
        int o = 64 + j0 * 256 + co4 * 4;
        *(float4*)&sm[o] = make_float4(
            fmaxf(aA[0] + b4.x, 0.f), fmaxf(aA[1] + b4.y, 0.f),
            fmaxf(aA[2] + b4.z, 0.f), fmaxf(aA[3] + b4.w, 0.f));
        *(float4*)&sm[SMB + o] = make_float4(
            fmaxf(aB[0] + b4.x, 0.f), fmaxf(aB[1] + b4.y, 0.f),
            fmaxf(aB[2] + b4.z, 0.f), fmaxf(aB[3] + b4.w, 0.f));
    }
    __syncthreads();

    // ---- L1: K=256 -> 128ch, 2 rows x 4 cols. 256 threads: (tap, co4, j).
    if (tid < 256) {
        const int t = tid >> 6, co4 = (tid >> 1) & 31, j = tid & 1;
        const int di = t >> 1, dj = t & 1, ft = 3 - t;
        const float* wp = W1 + (size_t)ft * 256 * 128 + co4 * 4;
        float aA[4] = {0.f,0.f,0.f,0.f}, aB[4] = {0.f,0.f,0.f,0.f};
        #pragma unroll 4
        for (int kq = 0; kq < 64; ++kq) {
            float4 xA = *(const float4*)&sm[64 + j * 256 + kq * 4];
            float4 xB = *(const float4*)&sm[SMB + 64 + j * 256 + kq * 4];
            #pragma unroll
            for (int kk = 0; kk < 4; ++kk) {
                float4 w4 = *(const float4*)&wp[(kq * 4 + kk) * 128];
                float xa = f4e(xA, kk), xb = f4e(xB, kk);
                aA[0] = fmaf(xa, w4.x, aA[0]); aA[1] = fmaf(xa, w4.y, aA[1]);
                aA[2] = fmaf(xa, w4.z, aA[2]); aA[3] = fmaf(xa, w4.w, aA[3]);
                aB[0] = fmaf(xb, w4.x, aB[0]); aB[1] = fmaf(xb, w4.y, aB[1]);
                aB[2] = fmaf(xb, w4.z, aB[2]); aB[3] = fmaf(xb, w4.w, aB[3]);
            }
        }
        float4 b4 = *(const float4*)&B1[co4 * 4];
        int o = 576 + (di * 4 + 2 * j + dj) * 132 + co4 * 4;
        *(float4*)&sm[o] = make_float4(
            fmaxf(aA[0] + b4.x, 0.f), fmaxf(aA[1] + b4.y, 0.f),
            fmaxf(aA[2] + b4.z, 0.f), fmaxf(aA[3] + b4.w, 0.f));
        *(float4*)&sm[SMB + o] = make_float4(
            fmaxf(aB[0] + b4.x, 0.f), fmaxf(aB[1] + b4.y, 0.f),
            fmaxf(aB[2] + b4.z, 0.f), fmaxf(aB[3] + b4.w, 0.f));
    }
    __syncthreads();

    // ---- L2: K=128 -> 64ch, 4 rows x 8 cols. 512 threads: (orow, ocol, co4).
    {
        const int orow = tid >> 7, ocol = (tid >> 4) & 7, co4 = tid & 15;
        const int i = orow >> 1, di = orow & 1, j = ocol >> 1, dj = ocol & 1;
        const int ft = 3 - (2 * di + dj);
        const float* wp = W2 + (size_t)ft * 128 * 64 + co4 * 4;
        float aA[4] = {0.f,0.f,0.f,0.f}, aB[4] = {0.f,0.f,0.f,0.f};
        #pragma unroll 4
        for (int kq = 0; kq < 32; ++kq) {
            float4 xA = *(const float4*)&sm[576 + (i * 4 + j) * 132 + kq * 4];
            float4 xB = *(const float4*)&sm[SMB + 576 + (i * 4 + j) * 132 + kq * 4];
            #pragma unroll
            for (int kk = 0; kk < 4; ++kk) {
                float4 w4 = *(const float4*)&wp[(kq * 4 + kk) * 64];
                float xa = f4e(xA, kk), xb = f4e(xB, kk);
                aA[0] = fmaf(xa, w4.x, aA[0]); aA[1] = fmaf(xa, w4.y, aA[1]);
                aA[2] = fmaf(xa, w4.z, aA[2]); aA[3] = fmaf(xa, w4.w, aA[3]);
                aB[0] = fmaf(xb, w4.x, aB[0]); aB[1] = fmaf(xb, w4.y, aB[1]);
                aB[2] = fmaf(xb, w4.z, aB[2]); aB[3] = fmaf(xb, w4.w, aB[3]);
            }
        }
        float4 b4 = *(const float4*)&B2[co4 * 4];
        int o = 1632 + (orow * 8 + ocol) * 68 + co4 * 4;
        *(float4*)&sm[o] = make_float4(
            fmaxf(aA[0] + b4.x, 0.f), fmaxf(aA[1] + b4.y, 0.f),
            fmaxf(aA[2] + b4.z, 0.f), fmaxf(aA[3] + b4.w, 0.f));
        *(float4*)&sm[SMB + o] = make_float4(
            fmaxf(aB[0] + b4.x, 0.f), fmaxf(aB[1] + b4.y, 0.f),
            fmaxf(aB[2] + b4.z, 0.f), fmaxf(aB[3] + b4.w, 0.f));
    }
    __syncthreads();

    // ---- Chunks: per c, L3 (2 rows) -> L4 (4 rows) -> L5 (8 final rows).
    const float b50 = B5[0], b51 = B5[1], b52 = B5[2];

    for (int c = 0; c < 4; ++c) {
        {   // L3: K=64 -> 32ch, rows 2c..2c+1 (input aL2 row c), 16 cols.
            // 512 threads: (r, x3, co2) -- co-tile 2 via float2 weights.
            const int co2 = tid & 15, x3 = (tid >> 4) & 15, r = tid >> 8;
            const int j = x3 >> 1, dj = x3 & 1;
            const int ft = 3 - (2 * r + dj);
            const float* wp = W3 + (size_t)ft * 64 * 32 + co2 * 2;
            float aA0 = 0.f, aA1 = 0.f, aB0 = 0.f, aB1 = 0.f;
            #pragma unroll 4
            for (int kq = 0; kq < 16; ++kq) {
                float4 xA = *(const float4*)&sm[1632 + (c * 8 + j) * 68 + kq * 4];
                float4 xB = *(const float4*)&sm[SMB + 1632 + (c * 8 + j) * 68 + kq * 4];
                #pragma unroll
                for (int kk = 0; kk < 4; ++kk) {
                    float2 w2 = *(const float2*)&wp[(kq * 4 + kk) * 32];
                    float xa = f4e(xA, kk), xb = f4e(xB, kk);
                    aA0 = fmaf(xa, w2.x, aA0); aA1 = fmaf(xa, w2.y, aA1);
                    aB0 = fmaf(xb, w2.x, aB0); aB1 = fmaf(xb, w2.y, aB1);
                }
            }
            float2 b2 = *(const float2*)&B3[co2 * 2];
            int o = (r * 16 + x3) * 36 + co2 * 2;
            *(float2*)&sm[o] = make_float2(fmaxf(aA0 + b2.x, 0.f), fmaxf(aA1 + b2.y, 0.f));
            *(float2*)&sm[SMB + o] = make_float2(fmaxf(aB0 + b2.x, 0.f), fmaxf(aB1 + b2.y, 0.f));
        }
        __syncthreads();
        {   // L4: K=32 -> 16ch, chunk rows 0..3, 32 cols. (ocol, orow, co4).
            const int co4 = tid & 3, orow = (tid >> 2) & 3, ocol = tid >> 4;
            const int il = orow >> 1, di = orow & 1;
            const int j = ocol >> 1, dj = ocol & 1;
            const int ft = 3 - (2 * di + dj);
            const float* wp = W4 + (size_t)ft * 32 * 16 + co4 * 4;
            float aA[4] = {0.f,0.f,0.f,0.f}, aB[4] = {0.f,0.f,0.f,0.f};
            #pragma unroll
            for (int kq = 0; kq < 8; ++kq) {
                float4 xA = *(const float4*)&sm[(il * 16 + j) * 36 + kq * 4];
                float4 xB = *(const float4*)&sm[SMB + (il * 16 + j) * 36 + kq * 4];
                #pragma unroll
                for (int kk = 0; kk < 4; ++kk) {
                    float4 w4 = *(const float4*)&wp[(kq * 4 + kk) * 16];
                    float xa = f4e(xA, kk), xb = f4e(xB, kk);
                    aA[0] = fmaf(xa, w4.x, aA[0]); aA[1] = fmaf(xa, w4.y, aA[1]);
                    aA[2] = fmaf(xa, w4.z, aA[2]); aA[3] = fmaf(xa, w4.w, aA[3]);
                    aB[0] = fmaf(xb, w4.x, aB[0]); aB[1] = fmaf(xb, w4.y, aB[1]);
                    aB[2] = fmaf(xb, w4.z, aB[2]); aB[3] = fmaf(xb, w4.w, aB[3]);
                }
            }
            float4 b4 = *(const float4*)&B4[co4 * 4];
            int o = 3808 + (orow * 32 + ocol) * 20 + co4 * 4;
            *(float4*)&sm[o] = make_float4(
                fmaxf(aA[0] + b4.x, 0.f), fmaxf(aA[1] + b4.y, 0.f),
                fmaxf(aA[2] + b4.z, 0.f), fmaxf(aA[3] + b4.w, 0.f));
            *(float4*)&sm[SMB + o] = make_float4(
                fmaxf(aB[0] + b4.x, 0.f), fmaxf(aB[1] + b4.y, 0.f),
                fmaxf(aB[2] + b4.z, 0.f), fmaxf(aB[3] + b4.w, 0.f));
        }
        __syncthreads();
        {   // L5: K=16 -> 3ch sigmoid; rows 8c..8c+7 (global 32s+8c+g5), col x5.
            const int x5 = tid & 63, g5 = tid >> 6;
            const int lr = g5 >> 1, j = x5 >> 1;
            const int di5 = g5 & 1, dj5 = x5 & 1;
            const int ft5 = 3 - (2 * di5 + dj5);
            float aA0 = b50, aA1 = b51, aA2 = b52;
            float aB0 = b50, aB1 = b51, aB2 = b52;
            #pragma unroll
            for (int kq = 0; kq < 4; ++kq) {
                float4 xA = *(const float4*)&sm[3808 + (lr * 32 + j) * 20 + kq * 4];
                float4 xB = *(const float4*)&sm[SMB + 3808 + (lr * 32 + j) * 20 + kq * 4];
                float4 w0 = *(const float4*)&sm[W5T + ft5 * 48 +  0 + kq * 4];
                float4 w1 = *(const float4*)&sm[W5T + ft5 * 48 + 16 + kq * 4];
                float4 w2 = *(const float4*)&sm[W5T + ft5 * 48 + 32 + kq * 4];
                #pragma unroll
                for (int kk = 0; kk < 4; ++kk) {
                    float xa = f4e(xA, kk), xb = f4e(xB, kk);
                    float e0 = f4e(w0, kk), e1 = f4e(w1, kk), e2 = f4e(w2, kk);
                    aA0 = fmaf(xa, e0, aA0); aA1 = fmaf(xa, e1, aA1); aA2 = fmaf(xa, e2, aA2);
                    aB0 = fmaf(xb, e0, aB0); aB1 = fmaf(xb, e1, aB1); aB2 = fmaf(xb, e2, aB2);
                }
            }
            int row = 32 * s + 8 * c + g5;
            float* dpA = dec + (size_t)inst0 * 12288 + (size_t)(row * 64 + x5) * 3;
            float* dpB = dec + (size_t)inst1 * 12288 + (size_t)(row * 64 + x5) * 3;
            dpA[0] = 1.0f / (1.0f + expf(-aA0));
            dpA[1] = 1.0f / (1.0f + expf(-aA1));
            dpA[2] = 1.0f / (1.0f + expf(-aA2));
            dpB[0] = 1.0f / (1.0f + expf(-aB0));
            dpB[1] = 1.0f / (1.0f + expf(-aB1));
            dpB[2] = 1.0f / (1.0f + expf(-aB2));
        }
        __syncthreads();
    }
}

// Fused STN bilinear sample + weighted composite + in-block reduce.
// grid 512 = (b, 16x8 px tile); 1024 threads = 8 box-splits x 128 px.
__global__ __launch_bounds__(1024) void composite_k(
    const float* __restrict__ dec, const float* __restrict__ wgt,
    const float* __restrict__ sxs, const float* __restrict__ oxs,
    const float* __restrict__ sys, const float* __restrict__ oys,
    const int* __restrict__ binst, const int* __restrict__ rect,
    const int* __restrict__ cidx, const int* __restrict__ cnt,
    float* __restrict__ out)
{
    __shared__ float pls[8][128][3];   // 12 KB

    int b = blockIdx.x >> 7, tile = blockIdx.x & 127;      // 8 x-tiles x 16 y-tiles
    int tx0 = (tile & 7) << 4, ty0 = (tile >> 3) << 3;     // 16 wide x 8 tall
    int s = threadIdx.x >> 7, px = threadIdx.x & 127;
    int lx = px & 15, ly = px >> 4;                        // 16 x 8
    int w = tx0 + lx, h = ty0 + ly;

    int nb = cnt[b];
    int lo = (nb * s) >> 3, hi = (nb * (s + 1)) >> 3;

    float fw = (float)w, fh = (float)h;
    float a0 = 0.f, a1 = 0.f, a2 = 0.f;
    for (int q = lo; q < hi; ++q) {
        int n = cidx[b * NBOX + q];
        int rc = rect[b * NBOX + n];
        int wlo = rc & 255, whi = (rc >> 8) & 255;
        int hlo = (rc >> 16) & 255, hhi = (rc >> 24) & 255;
        if (whi < tx0 || wlo > tx0 + 15 || hhi < ty0 || hlo > ty0 + 7) continue;
        int g = b * NBOX + n;
        float wg = wgt[g];
        float pxx = fmaf(fw, sxs[g], oxs[g]);
        float pyy = fmaf(fh, sys[g], oys[g]);
        float x0 = floorf(pxx), y0 = floorf(pyy);
        if (x0 < -1.0f || x0 > 63.0f || y0 < -1.0f || y0 > 63.0f) continue;
        float wx = pxx - x0, wy = pyy - y0;
        int ix = (int)x0, iy = (int)y0;
        int x0c = max(ix, 0), x1c = min(ix + 1, 63);
        int y0c = max(iy, 0), y1c = min(iy + 1, 63);
        float m00 = (ix >= 0 && iy >= 0) ? 1.f : 0.f;
        float m01 = (ix + 1 <= 63 && iy >= 0) ? 1.f : 0.f;
        float m10 = (ix >= 0 && iy + 1 <= 63) ? 1.f : 0.f;
        float m11 = (ix + 1 <= 63 && iy + 1 <= 63) ? 1.f : 0.f;
        float w00 = (1.f - wy) * (1.f - wx) * m00;
        float w01 = (1.f - wy) * wx * m01;
        float w10 = wy * (1.f - wx) * m10;
        float w11 = wy * wx * m11;
        const float* img = dec + (size_t)binst[g] * 12288;   // (64,64,3) HWC
        int b00 = (y0c * 64 + x0c) * 3, b01 = (y0c * 64 + x1c) * 3;
        int b10 = (y1c * 64 + x0c) * 3, b11 = (y1c * 64 + x1c) * 3;
        a0 += wg * (w00 * img[b00]   + w01 * img[b01]   + w10 * img[b10]   + w11 * img[b11]);
        a1 += wg * (w00 * img[b00+1] + w01 * img[b01+1] + w10 * img[b10+1] + w11 * img[b11+1]);
        a2 += wg * (w00 * img[b00+2] + w01 * img[b01+2] + w10 * img[b10+2] + w11 * img[b11+2]);
    }
    pls[s][px][0] = a0; pls[s][px][1] = a1; pls[s][px][2] = a2;
    __syncthreads();

    if (threadIdx.x < 384) {
        int c = threadIdx.x >> 7, p2 = threadIdx.x & 127;
        float v = 0.f;
        #pragma unroll
        for (int t = 0; t < 8; ++t) v += pls[t][p2][c];
        int h2 = ty0 + (p2 >> 4), w2 = tx0 + (p2 & 15);
        out[((b * 3 + c) * 128 + h2) * 128 + w2] = v;
    }
}

extern "C" void kernel_launch(void* const* d_in, const int* in_sizes, int n_in,
                              void* d_out, int out_size, void* d_ws, size_t ws_size,
                              hipStream_t stream)
{
    const float* z_what    = (const float*)d_in[0];   // (4,85,64)
    const float* z_where   = (const float*)d_in[1];   // (4,380,4)
    const int*   z_present = (const int*)  d_in[2];   // (4,380,1)
    const float* z_depth   = (const float*)d_in[3];   // (4,85,1)

    // workspace: dec 16.71 MB | params ~55 KB
    char* ws = (char*)d_ws;
    float* dec = (float*)ws;                           // 340*12288 f32
    float* P   = (float*)(ws + 16711680);
    float* wgt = P,        *sxs = P + 1520, *oxs = P + 2 * 1520;
    float* sys = P + 3 * 1520, *oys = P + 4 * 1520;
    int* binst = (int*)(P + 5 * 1520);
    int* rect  = binst + 1520;
    int* cidx  = binst + 2 * 1520;
    int* cnt   = binst + 3 * 1520;

    decode_fused_k<<<dim3(NINST + 4), dim3(512), 0, stream>>>(
        z_what,
        (const float*)d_in[4],  (const float*)d_in[5],
        (const float*)d_in[6],  (const float*)d_in[7],
        (const float*)d_in[8],  (const float*)d_in[9],
        (const float*)d_in[10], (const float*)d_in[11],
        (const float*)d_in[12], (const float*)d_in[13],
        (const float*)d_in[14], (const float*)d_in[15],
        z_where, z_present, z_depth,
        wgt, sxs, oxs, sys, oys, binst, rect, cidx, cnt,
        dec);

    composite_k<<<dim3(512), dim3(1024), 0, stream>>>(
        dec, wgt, sxs, oxs, sys, oys, binst, rect, cidx, cnt, (float*)d_out);
}

// Round 16
// 87.534 us; speedup vs baseline: 1.3734x; 1.3734x over previous
//
#include <hip/hip_runtime.h>
#include <hip/hip_bf16.h>

#define NBOX  380
#define NLOCS 85
#define NINST 340   // B(4) * NLOCS(85)

// box index -> location index (from _recon_indices structure)
__device__ __forceinline__ int loc_of_box(int n) {
    if (n < 256) return n >> 2;               // fm=8, 4 boxes/loc
    if (n < 352) return 64 + (n - 256) / 6;   // fm=4, 6 boxes/loc
    if (n < 376) return 80 + (n - 352) / 6;   // fm=2, 6 boxes/loc
    return 84;                                // fm=1, 4 boxes/loc
}

// Per-batch softmax over depths + per-box affine params + rect + compaction.
// 512 threads. Uses sm[0..896).
__device__ void box_params_dev(int b, const float* __restrict__ zwhere,
    const int* __restrict__ zpresent, const float* __restrict__ zdepth,
    float* wgt, float* sxs, float* oxs, float* sys, float* oys,
    int* binst, int* rect, int* cidx, int* cnt, float* sm)
{
    float* sd  = sm;         // 384 (380 used)
    float* red = sm + 384;   // 512
    const int tid = threadIdx.x;

    if (tid < NBOX) {
        int loc = loc_of_box(tid);
        sd[tid] = (zpresent[b * NBOX + tid] == 1) ? zdepth[b * NLOCS + loc] : -1000.0f;
    }
    __syncthreads();

    float m = (tid < NBOX) ? sd[tid] : -1e30f;
    red[tid] = m; __syncthreads();
    for (int s = 256; s > 0; s >>= 1) {
        if (tid < s) red[tid] = fmaxf(red[tid], red[tid + s]);
        __syncthreads();
    }
    m = red[0]; __syncthreads();

    float sum = (tid < NBOX) ? expf(sd[tid] - m) : 0.f;
    red[tid] = sum; __syncthreads();
    for (int s = 256; s > 0; s >>= 1) {
        if (tid < s) red[tid] += red[tid + s];
        __syncthreads();
    }
    float inv = 1.0f / red[0];
    __syncthreads();

    if (tid < NBOX) {
        int g = b * NBOX + tid;
        float wv = expf(sd[tid] - m) * inv;   // exp(-1000-m) underflows to exactly 0
        wgt[g] = wv;
        float cx = zwhere[g * 4 + 0], cy = zwhere[g * 4 + 1];
        float w  = zwhere[g * 4 + 2], h  = zwhere[g * 4 + 3];
        float isx = 1.0f / fmaxf(w, 1e-5f);
        float isy = 1.0f / fmaxf(h, 1e-5f);
        float sxv = isx * (63.0f / 127.0f);
        float oxv = 31.5f * (1.0f - 2.0f * cx * isx);
        float syv = isy * (63.0f / 127.0f);
        float oyv = 31.5f * (1.0f - 2.0f * cy * isy);
        sxs[g] = sxv; oxs[g] = oxv; sys[g] = syv; oys[g] = oyv;
        binst[g] = b * NLOCS + loc_of_box(tid);
        int wlo = min(127, max(0, (int)floorf((-1.0f - oxv) / sxv)));
        int whi = max(0, min(127, (int)ceilf((64.0f - oxv) / sxv)));
        int hlo = min(127, max(0, (int)floorf((-1.0f - oyv) / syv)));
        int hhi = max(0, min(127, (int)ceilf((64.0f - oyv) / syv)));
        rect[g] = wlo | (whi << 8) | (hlo << 16) | (hhi << 24);
        sd[tid] = wv;   // presence flag for compaction
    }
    __syncthreads();

    if (tid < 64) {   // wave 0: deterministic ascending compaction
        int base = 0;
        for (int c = 0; c < 6; ++c) {
            int n = c * 64 + tid;
            bool p = (n < NBOX) && (sd[n] > 0.0f);
            unsigned long long mask = __ballot(p);
            int pos = __popcll(mask & ((1ull << tid) - 1ull));
            if (p) cidx[b * NBOX + base + pos] = n;
            base += __popcll(mask);
        }
        if (tid == 0) cnt[b] = base;
    }
}

// Whole decoder (L0..L5) for ONE instance per block (512 threads, 8 waves).
// *** This is the R9 kernel verbatim — measured 59.1±0.3 us steady-state,
// VGPR 52, LDS 49,664 B, FETCH 4.1 MB (no spill), 174K bank conflicts. ***
// R10 (4-way split), R13/R14 (co-tile-4 weights) all regressed vs this:
// split pays linear weight re-streaming; co-tile hit spill (R13: VGPR=128
// cap, +24MB scratch) then bank conflicts (R14: 1.59M, strides sharing
// factors with 32). Decode sits at its LDS-instruction-pipe basin here.
// out[(2i+di, 2j+dj)][co] = act( b[co] + sum_k x[i,j][k] * W[1-di][1-dj][k][co] )
// tap t = 2di+dj, flipped weight index ft = 3-t.
// LDS overlay (floats): [0..4224) L2o[64][66] / L4b[16][258]
//                       [4224..12416) L3o[32][256] / {s_x 64 | L0o[4][256] | L1o[16][128]}
// NOTE (R8): register arrays must be static-indexed — L5 k-loop FULL unroll
// only, else w5r goes to scratch (+33.8 MB writes).
__global__ __launch_bounds__(512, 2) void decode_fused_k(
    const float* __restrict__ z_what,
    const float* __restrict__ W0, const float* __restrict__ B0,
    const float* __restrict__ W1, const float* __restrict__ B1,
    const float* __restrict__ W2, const float* __restrict__ B2,
    const float* __restrict__ W3, const float* __restrict__ B3,
    const float* __restrict__ W4, const float* __restrict__ B4,
    const float* __restrict__ W5, const float* __restrict__ B5,
    const float* __restrict__ z_where, const int* __restrict__ z_present,
    const float* __restrict__ z_depth,
    float* __restrict__ wgt, float* __restrict__ sxs, float* __restrict__ oxs,
    float* __restrict__ sys, float* __restrict__ oys, int* __restrict__ binst,
    int* __restrict__ rect, int* __restrict__ cidx, int* __restrict__ cnt,
    float* __restrict__ dec)
{
    __shared__ __align__(16) float sm[12416];   // 49,664 B

    if (blockIdx.x >= NINST) {   // 4 trailing blocks: box params
        box_params_dev(blockIdx.x - NINST, z_where, z_present, z_depth,
                       wgt, sxs, oxs, sys, oys, binst, rect, cidx, cnt, sm);
        return;
    }

    float* L2o = sm;            // [64 ch][66 px]
    float* s_x = sm + 4224;     // [64]
    float* L0o = sm + 4288;     // [4 px][256 ch]
    float* L1o = sm + 5312;     // [16 px][128 ch]
    float* L3o = sm + 4224;     // [32 ch][256 px]  (overlays s_x/L0o/L1o)
    float* L4b = sm;            // [16 ch][258 px]  (overlays L2o)

    const int inst = blockIdx.x;
    const int tid = threadIdx.x;
    const int lane = tid & 63;
    const int wv = __builtin_amdgcn_readfirstlane(tid >> 6);   // 0..7

    if (tid < 64) s_x[tid] = z_what[inst * 64 + tid];
    __syncthreads();

    // ---- L0: K=64 -> 256co, 1px -> 2x2. thread = (tap-group, co); 2 taps each.
    {
        const int co = tid & 255;
        const int tg = __builtin_amdgcn_readfirstlane(tid >> 8);   // taps tg, tg+2
        const float* wA = W0 + (size_t)(3 - tg) * 64 * 256 + co;   // ft = 3-tg
        const float* wB = W0 + (size_t)(1 - tg) * 64 * 256 + co;   // ft = 3-(tg+2)
        float a0 = 0.f, a1 = 0.f;
        #pragma unroll 8
        for (int k = 0; k < 64; ++k) {
            float xv = s_x[k];
            a0 = fmaf(xv, wA[k * 256], a0);
            a1 = fmaf(xv, wB[k * 256], a1);
        }
        float bb = B0[co];
        L0o[tg * 256 + co]       = fmaxf(a0 + bb, 0.f);
        L0o[(tg + 2) * 256 + co] = fmaxf(a1 + bb, 0.f);
    }
    __syncthreads();

    // ---- L1: K=256 -> 128co, 2x2 -> 4x4. thread = (tap, co); 4 input px each.
    {
        const int co = tid & 127;
        const int t = __builtin_amdgcn_readfirstlane(tid >> 7);    // 0..3
        const int ft = 3 - t, di = t >> 1, dj = t & 1;
        const float* wp = W1 + (size_t)ft * 256 * 128 + co;
        float acc[4] = {0.f, 0.f, 0.f, 0.f};
        #pragma unroll 2
        for (int q = 0; q < 64; ++q) {
            int k0 = q * 4;
            float4 x0 = *(const float4*)&L0o[0 * 256 + k0];
            float4 x1 = *(const float4*)&L0o[1 * 256 + k0];
            float4 x2 = *(const float4*)&L0o[2 * 256 + k0];
            float4 x3 = *(const float4*)&L0o[3 * 256 + k0];
            float w0 = wp[(k0 + 0) * 128], w1 = wp[(k0 + 1) * 128];
            float w2 = wp[(k0 + 2) * 128], w3 = wp[(k0 + 3) * 128];
            acc[0] = fmaf(x0.x, w0, acc[0]); acc[0] = fmaf(x0.y, w1, acc[0]);
            acc[0] = fmaf(x0.z, w2, acc[0]); acc[0] = fmaf(x0.w, w3, acc[0]);
            acc[1] = fmaf(x1.x, w0, acc[1]); acc[1] = fmaf(x1.y, w1, acc[1]);
            acc[1] = fmaf(x1.z, w2, acc[1]); acc[1] = fmaf(x1.w, w3, acc[1]);
            acc[2] = fmaf(x2.x, w0, acc[2]); acc[2] = fmaf(x2.y, w1, acc[2]);
            acc[2] = fmaf(x2.z, w2, acc[2]); acc[2] = fmaf(x2.w, w3, acc[2]);
            acc[3] = fmaf(x3.x, w0, acc[3]); acc[3] = fmaf(x3.y, w1, acc[3]);
            acc[3] = fmaf(x3.z, w2, acc[3]); acc[3] = fmaf(x3.w, w3, acc[3]);
        }
        float bb = B1[co];
        #pragma unroll
        for (int p = 0; p < 4; ++p) {
            int i = p >> 1, j = p & 1;
            L1o[((2 * i + di) * 4 + 2 * j + dj) * 128 + co] = fmaxf(acc[p] + bb, 0.f);
        }
    }
    __syncthreads();

    // ---- L2: K=128 -> 64co, 4x4 -> 8x8. wave = (tap, px-half); lane = co.
    {
        const int co = lane;
        const int t = wv & 3, ih = wv >> 2;
        const int ft = 3 - t, di = t >> 1, dj = t & 1;
        const float* wp = W2 + (size_t)ft * 128 * 64 + co;
        float acc[8] = {0.f,0.f,0.f,0.f,0.f,0.f,0.f,0.f};
        #pragma unroll 2
        for (int q = 0; q < 32; ++q) {
            int k0 = q * 4;
            float w0 = wp[(k0 + 0) * 64], w1 = wp[(k0 + 1) * 64];
            float w2 = wp[(k0 + 2) * 64], w3 = wp[(k0 + 3) * 64];
            #pragma unroll
            for (int pp = 0; pp < 8; ++pp) {
                float4 xq = *(const float4*)&L1o[(ih * 8 + pp) * 128 + k0];
                acc[pp] = fmaf(xq.x, w0, acc[pp]);
                acc[pp] = fmaf(xq.y, w1, acc[pp]);
                acc[pp] = fmaf(xq.z, w2, acc[pp]);
                acc[pp] = fmaf(xq.w, w3, acc[pp]);
            }
        }
        float bb = B2[co];
        #pragma unroll
        for (int pp = 0; pp < 8; ++pp) {
            int p = ih * 8 + pp;
            int i = p >> 2, j = p & 3;
            int op = (2 * i + di) * 8 + 2 * j + dj;
            L2o[co * 66 + op] = fmaxf(acc[pp] + bb, 0.f);
        }
    }
    __syncthreads();

    // ---- L3: K=64 -> 32co, 8x8 -> 16x16. wave = (di, co-quarter); lane = px.
    {
        const int di = wv >> 2, coq = wv & 3;
        const int ft0 = 3 - 2 * di, ft1 = 2 - 2 * di;   // dj = 0 / 1
        const float* w0b = W3 + (size_t)ft0 * 64 * 32 + coq * 8;
        const float* w1b = W3 + (size_t)ft1 * 64 * 32 + coq * 8;
        float a0[8], a1[8];
        #pragma unroll
        for (int c = 0; c < 8; ++c) { a0[c] = 0.f; a1[c] = 0.f; }
        #pragma unroll 4
        for (int k = 0; k < 64; ++k) {
            float xv = L2o[k * 66 + lane];
            const float* w0p = w0b + k * 32;
            const float* w1p = w1b + k * 32;
            #pragma unroll
            for (int c = 0; c < 8; ++c) {
                a0[c] = fmaf(xv, w0p[c], a0[c]);
                a1[c] = fmaf(xv, w1p[c], a1[c]);
            }
        }
        int i = lane >> 3, j = lane & 7;
        #pragma unroll
        for (int c = 0; c < 8; ++c) {
            float bb = B3[coq * 8 + c];
            float2 v = make_float2(fmaxf(a0[c] + bb, 0.f), fmaxf(a1[c] + bb, 0.f));
            *(float2*)&L3o[(coq * 8 + c) * 256 + (2 * i + di) * 16 + 2 * j] = v;
        }
    }
    __syncthreads();

    // ---- L4 (K=32 -> 16co, 16x16 -> 32x32) + L5 (K=16 -> 3, sigmoid), 4 chunks.
    const int t5 = wv & 3, pxh5 = wv >> 2;
    const int ft5 = 3 - t5, di5 = t5 >> 1, dj5 = t5 & 1;
    float w5r[16][3];
    #pragma unroll
    for (int k = 0; k < 16; ++k)
        #pragma unroll
        for (int c = 0; c < 3; ++c)
            w5r[k][c] = W5[(ft5 * 16 + k) * 3 + c];
    const float b50 = B5[0], b51 = B5[1], b52 = B5[2];

    for (int c4 = 0; c4 < 4; ++c4) {
        {   // L4 on input rows 4c4..4c4+3. wave = (di, co-quarter); lane = px.
            const int di4 = wv >> 2, coq4 = wv & 3;
            const int ft0 = 3 - 2 * di4, ft1 = 2 - 2 * di4;
            const float* w0b = W4 + (size_t)ft0 * 32 * 16 + coq4 * 4;
            const float* w1b = W4 + (size_t)ft1 * 32 * 16 + coq4 * 4;
            float a0[4], a1[4];
            #pragma unroll
            for (int c = 0; c < 4; ++c) { a0[c] = 0.f; a1[c] = 0.f; }
            #pragma unroll 4
            for (int k = 0; k < 32; ++k) {
                float xv = L3o[k * 256 + 64 * c4 + lane];
                const float* w0p = w0b + k * 16;
                const float* w1p = w1b + k * 16;
                #pragma unroll
                for (int c = 0; c < 4; ++c) {
                    a0[c] = fmaf(xv, w0p[c], a0[c]);
                    a1[c] = fmaf(xv, w1p[c], a1[c]);
                }
            }
            int il = lane >> 4, j = lane & 15;
            #pragma unroll
            for (int c = 0; c < 4; ++c) {
                float bb = B4[coq4 * 4 + c];
                float2 v = make_float2(fmaxf(a0[c] + bb, 0.f), fmaxf(a1[c] + bb, 0.f));
                *(float2*)&L4b[(coq4 * 4 + c) * 258 + (2 * il + di4) * 32 + 2 * j] = v;
            }
        }
        __syncthreads();
        {   // L5: wave = (tap, px-half); 2 sub-rounds of 64 px.
            #pragma unroll
            for (int sub = 0; sub < 2; ++sub) {
                int pl = pxh5 * 128 + sub * 64 + lane;
                int r = pl >> 5, x5 = pl & 31;
                int y5 = 8 * c4 + r;
                float a0 = b50, a1 = b51, a2 = b52;
                #pragma unroll   // FULL unroll required: w5r[k] must be static-indexed
                for (int k = 0; k < 16; ++k) {
                    float xv = L4b[k * 258 + pl];
                    a0 = fmaf(xv, w5r[k][0], a0);
                    a1 = fmaf(xv, w5r[k][1], a1);
                    a2 = fmaf(xv, w5r[k][2], a2);
                }
                a0 = 1.0f / (1.0f + expf(-a0));
                a1 = 1.0f / (1.0f + expf(-a1));
                a2 = 1.0f / (1.0f + expf(-a2));
                float* dp = dec + (size_t)inst * 12288
                          + (size_t)((2 * y5 + di5) * 64 + 2 * x5 + dj5) * 3;
                dp[0] = a0; dp[1] = a1; dp[2] = a2;
            }
        }
        __syncthreads();
    }
}

// Fused STN bilinear sample + weighted composite + in-block reduce.
// *** R11 composite verbatim — 8 box-splits x 128 px, grid 512, ~24 us. ***
__global__ __launch_bounds__(1024) void composite_k(
    const float* __restrict__ dec, const float* __restrict__ wgt,
    const float* __restrict__ sxs, const float* __restrict__ oxs,
    const float* __restrict__ sys, const float* __restrict__ oys,
    const int* __restrict__ binst, const int* __restrict__ rect,
    const int* __restrict__ cidx, const int* __restrict__ cnt,
    float* __restrict__ out)
{
    __shared__ float pls[8][128][3];   // 12 KB

    int b = blockIdx.x >> 7, tile = blockIdx.x & 127;      // 8 x-tiles x 16 y-tiles
    int tx0 = (tile & 7) << 4, ty0 = (tile >> 3) << 3;     // 16 wide x 8 tall
    int s = threadIdx.x >> 7, px = threadIdx.x & 127;
    int lx = px & 15, ly = px >> 4;                        // 16 x 8
    int w = tx0 + lx, h = ty0 + ly;

    int nb = cnt[b];
    int lo = (nb * s) >> 3, hi = (nb * (s + 1)) >> 3;

    float fw = (float)w, fh = (float)h;
    float a0 = 0.f, a1 = 0.f, a2 = 0.f;
    for (int q = lo; q < hi; ++q) {
        int n = cidx[b * NBOX + q];
        int rc = rect[b * NBOX + n];
        int wlo = rc & 255, whi = (rc >> 8) & 255;
        int hlo = (rc >> 16) & 255, hhi = (rc >> 24) & 255;
        if (whi < tx0 || wlo > tx0 + 15 || hhi < ty0 || hlo > ty0 + 7) continue;
        int g = b * NBOX + n;
        float wg = wgt[g];
        float pxx = fmaf(fw, sxs[g], oxs[g]);
        float pyy = fmaf(fh, sys[g], oys[g]);
        float x0 = floorf(pxx), y0 = floorf(pyy);
        if (x0 < -1.0f || x0 > 63.0f || y0 < -1.0f || y0 > 63.0f) continue;
        float wx = pxx - x0, wy = pyy - y0;
        int ix = (int)x0, iy = (int)y0;
        int x0c = max(ix, 0), x1c = min(ix + 1, 63);
        int y0c = max(iy, 0), y1c = min(iy + 1, 63);
        float m00 = (ix >= 0 && iy >= 0) ? 1.f : 0.f;
        float m01 = (ix + 1 <= 63 && iy >= 0) ? 1.f : 0.f;
        float m10 = (ix >= 0 && iy + 1 <= 63) ? 1.f : 0.f;
        float m11 = (ix + 1 <= 63 && iy + 1 <= 63) ? 1.f : 0.f;
        float w00 = (1.f - wy) * (1.f - wx) * m00;
        float w01 = (1.f - wy) * wx * m01;
        float w10 = wy * (1.f - wx) * m10;
        float w11 = wy * wx * m11;
        const float* img = dec + (size_t)binst[g] * 12288;   // (64,64,3) HWC
        int b00 = (y0c * 64 + x0c) * 3, b01 = (y0c * 64 + x1c) * 3;
        int b10 = (y1c * 64 + x0c) * 3, b11 = (y1c * 64 + x1c) * 3;
        a0 += wg * (w00 * img[b00]   + w01 * img[b01]   + w10 * img[b10]   + w11 * img[b11]);
        a1 += wg * (w00 * img[b00+1] + w01 * img[b01+1] + w10 * img[b10+1] + w11 * img[b11+1]);
        a2 += wg * (w00 * img[b00+2] + w01 * img[b01+2] + w10 * img[b10+2] + w11 * img[b11+2]);
    }
    pls[s][px][0] = a0; pls[s][px][1] = a1; pls[s][px][2] = a2;
    __syncthreads();

    if (threadIdx.x < 384) {
        int c = threadIdx.x >> 7, p2 = threadIdx.x & 127;
        float v = 0.f;
        #pragma unroll
        for (int t = 0; t < 8; ++t) v += pls[t][p2][c];
        int h2 = ty0 + (p2 >> 4), w2 = tx0 + (p2 & 15);
        out[((b * 3 + c) * 128 + h2) * 128 + w2] = v;
    }
}

extern "C" void kernel_launch(void* const* d_in, const int* in_sizes, int n_in,
                              void* d_out, int out_size, void* d_ws, size_t ws_size,
                              hipStream_t stream)
{
    const float* z_what    = (const float*)d_in[0];   // (4,85,64)
    const float* z_where   = (const float*)d_in[1];   // (4,380,4)
    const int*   z_present = (const int*)  d_in[2];   // (4,380,1)
    const float* z_depth   = (const float*)d_in[3];   // (4,85,1)

    // workspace: dec 16.71 MB | params ~55 KB
    char* ws = (char*)d_ws;
    float* dec = (float*)ws;                           // 340*12288 f32
    float* P   = (float*)(ws + 16711680);
    float* wgt = P,        *sxs = P + 1520, *oxs = P + 2 * 1520;
    float* sys = P + 3 * 1520, *oys = P + 4 * 1520;
    int* binst = (int*)(P + 5 * 1520);
    int* rect  = binst + 1520;
    int* cidx  = binst + 2 * 1520;
    int* cnt   = binst + 3 * 1520;

    decode_fused_k<<<dim3(NINST + 4), dim3(512), 0, stream>>>(
        z_what,
        (const float*)d_in[4],  (const float*)d_in[5],
        (const float*)d_in[6],  (const float*)d_in[7],
        (const float*)d_in[8],  (const float*)d_in[9],
        (const float*)d_in[10], (const float*)d_in[11],
        (const float*)d_in[12], (const float*)d_in[13],
        (const float*)d_in[14], (const float*)d_in[15],
        z_where, z_present, z_depth,
        wgt, sxs, oxs, sys, oys, binst, rect, cidx, cnt,
        dec);

    composite_k<<<dim3(512), dim3(1024), 0, stream>>>(
        dec, wgt, sxs, oxs, sys, oys, binst, rect, cidx, cnt, (float*)d_out);
}

// Round 17
// 87.474 us; speedup vs baseline: 1.3743x; 1.0007x over previous
//
#include <hip/hip_runtime.h>
#include <hip/hip_bf16.h>

#define NBOX  380
#define NLOCS 85
#define NINST 340   // B(4) * NLOCS(85)

// box index -> location index (from _recon_indices structure)
__device__ __forceinline__ int loc_of_box(int n) {
    if (n < 256) return n >> 2;               // fm=8, 4 boxes/loc
    if (n < 352) return 64 + (n - 256) / 6;   // fm=4, 6 boxes/loc
    if (n < 376) return 80 + (n - 352) / 6;   // fm=2, 6 boxes/loc
    return 84;                                // fm=1, 4 boxes/loc
}

// Per-batch softmax over depths + per-box affine params + rect + compaction.
// 512 threads. Uses sm[0..896).
__device__ void box_params_dev(int b, const float* __restrict__ zwhere,
    const int* __restrict__ zpresent, const float* __restrict__ zdepth,
    float* wgt, float* sxs, float* oxs, float* sys, float* oys,
    int* binst, int* rect, int* cidx, int* cnt, float* sm)
{
    float* sd  = sm;         // 384 (380 used)
    float* red = sm + 384;   // 512
    const int tid = threadIdx.x;

    if (tid < NBOX) {
        int loc = loc_of_box(tid);
        sd[tid] = (zpresent[b * NBOX + tid] == 1) ? zdepth[b * NLOCS + loc] : -1000.0f;
    }
    __syncthreads();

    float m = (tid < NBOX) ? sd[tid] : -1e30f;
    red[tid] = m; __syncthreads();
    for (int s = 256; s > 0; s >>= 1) {
        if (tid < s) red[tid] = fmaxf(red[tid], red[tid + s]);
        __syncthreads();
    }
    m = red[0]; __syncthreads();

    float sum = (tid < NBOX) ? expf(sd[tid] - m) : 0.f;
    red[tid] = sum; __syncthreads();
    for (int s = 256; s > 0; s >>= 1) {
        if (tid < s) red[tid] += red[tid + s];
        __syncthreads();
    }
    float inv = 1.0f / red[0];
    __syncthreads();

    if (tid < NBOX) {
        int g = b * NBOX + tid;
        float wv = expf(sd[tid] - m) * inv;   // exp(-1000-m) underflows to exactly 0
        wgt[g] = wv;
        float cx = zwhere[g * 4 + 0], cy = zwhere[g * 4 + 1];
        float w  = zwhere[g * 4 + 2], h  = zwhere[g * 4 + 3];
        float isx = 1.0f / fmaxf(w, 1e-5f);
        float isy = 1.0f / fmaxf(h, 1e-5f);
        float sxv = isx * (63.0f / 127.0f);
        float oxv = 31.5f * (1.0f - 2.0f * cx * isx);
        float syv = isy * (63.0f / 127.0f);
        float oyv = 31.5f * (1.0f - 2.0f * cy * isy);
        sxs[g] = sxv; oxs[g] = oxv; sys[g] = syv; oys[g] = oyv;
        binst[g] = b * NLOCS + loc_of_box(tid);
        int wlo = min(127, max(0, (int)floorf((-1.0f - oxv) / sxv)));
        int whi = max(0, min(127, (int)ceilf((64.0f - oxv) / sxv)));
        int hlo = min(127, max(0, (int)floorf((-1.0f - oyv) / syv)));
        int hhi = max(0, min(127, (int)ceilf((64.0f - oyv) / syv)));
        rect[g] = wlo | (whi << 8) | (hlo << 16) | (hhi << 24);
        sd[tid] = wv;   // presence flag for compaction
    }
    __syncthreads();

    if (tid < 64) {   // wave 0: deterministic ascending compaction
        int base = 0;
        for (int c = 0; c < 6; ++c) {
            int n = c * 64 + tid;
            bool p = (n < NBOX) && (sd[n] > 0.0f);
            unsigned long long mask = __ballot(p);
            int pos = __popcll(mask & ((1ull << tid) - 1ull));
            if (p) cidx[b * NBOX + base + pos] = n;
            base += __popcll(mask);
        }
        if (tid == 0) cnt[b] = base;
    }
}

// Whole decoder (L0..L5) for ONE instance per block (512 threads, 8 waves).
// R9 structure (measured 59.1±0.3 us, VGPR 52, LDS 49,664 B, no spill) —
// decode is LDS-instruction-pipe bound here; R10/R13/R14 restructures all
// regressed (split weight re-streaming / spill / bank conflicts).
// ONLY change vs R16: dec is now 4-channel padded (stride 16384 floats per
// instance, (64,64,4) HWC) and L5 writes ONE float4 store per px instead of
// 3 scalar stores.
// out[(2i+di, 2j+dj)][co] = act( b[co] + sum_k x[i,j][k] * W[1-di][1-dj][k][co] )
// LDS overlay (floats): [0..4224) L2o[64][66] / L4b[16][258]
//                       [4224..12416) L3o[32][256] / {s_x 64 | L0o[4][256] | L1o[16][128]}
// NOTE (R8): register arrays must be static-indexed — L5 k-loop FULL unroll.
__global__ __launch_bounds__(512, 2) void decode_fused_k(
    const float* __restrict__ z_what,
    const float* __restrict__ W0, const float* __restrict__ B0,
    const float* __restrict__ W1, const float* __restrict__ B1,
    const float* __restrict__ W2, const float* __restrict__ B2,
    const float* __restrict__ W3, const float* __restrict__ B3,
    const float* __restrict__ W4, const float* __restrict__ B4,
    const float* __restrict__ W5, const float* __restrict__ B5,
    const float* __restrict__ z_where, const int* __restrict__ z_present,
    const float* __restrict__ z_depth,
    float* __restrict__ wgt, float* __restrict__ sxs, float* __restrict__ oxs,
    float* __restrict__ sys, float* __restrict__ oys, int* __restrict__ binst,
    int* __restrict__ rect, int* __restrict__ cidx, int* __restrict__ cnt,
    float* __restrict__ dec)
{
    __shared__ __align__(16) float sm[12416];   // 49,664 B

    if (blockIdx.x >= NINST) {   // 4 trailing blocks: box params
        box_params_dev(blockIdx.x - NINST, z_where, z_present, z_depth,
                       wgt, sxs, oxs, sys, oys, binst, rect, cidx, cnt, sm);
        return;
    }

    float* L2o = sm;            // [64 ch][66 px]
    float* s_x = sm + 4224;     // [64]
    float* L0o = sm + 4288;     // [4 px][256 ch]
    float* L1o = sm + 5312;     // [16 px][128 ch]
    float* L3o = sm + 4224;     // [32 ch][256 px]  (overlays s_x/L0o/L1o)
    float* L4b = sm;            // [16 ch][258 px]  (overlays L2o)

    const int inst = blockIdx.x;
    const int tid = threadIdx.x;
    const int lane = tid & 63;
    const int wv = __builtin_amdgcn_readfirstlane(tid >> 6);   // 0..7

    if (tid < 64) s_x[tid] = z_what[inst * 64 + tid];
    __syncthreads();

    // ---- L0: K=64 -> 256co, 1px -> 2x2. thread = (tap-group, co); 2 taps each.
    {
        const int co = tid & 255;
        const int tg = __builtin_amdgcn_readfirstlane(tid >> 8);   // taps tg, tg+2
        const float* wA = W0 + (size_t)(3 - tg) * 64 * 256 + co;   // ft = 3-tg
        const float* wB = W0 + (size_t)(1 - tg) * 64 * 256 + co;   // ft = 3-(tg+2)
        float a0 = 0.f, a1 = 0.f;
        #pragma unroll 8
        for (int k = 0; k < 64; ++k) {
            float xv = s_x[k];
            a0 = fmaf(xv, wA[k * 256], a0);
            a1 = fmaf(xv, wB[k * 256], a1);
        }
        float bb = B0[co];
        L0o[tg * 256 + co]       = fmaxf(a0 + bb, 0.f);
        L0o[(tg + 2) * 256 + co] = fmaxf(a1 + bb, 0.f);
    }
    __syncthreads();

    // ---- L1: K=256 -> 128co, 2x2 -> 4x4. thread = (tap, co); 4 input px each.
    {
        const int co = tid & 127;
        const int t = __builtin_amdgcn_readfirstlane(tid >> 7);    // 0..3
        const int ft = 3 - t, di = t >> 1, dj = t & 1;
        const float* wp = W1 + (size_t)ft * 256 * 128 + co;
        float acc[4] = {0.f, 0.f, 0.f, 0.f};
        #pragma unroll 2
        for (int q = 0; q < 64; ++q) {
            int k0 = q * 4;
            float4 x0 = *(const float4*)&L0o[0 * 256 + k0];
            float4 x1 = *(const float4*)&L0o[1 * 256 + k0];
            float4 x2 = *(const float4*)&L0o[2 * 256 + k0];
            float4 x3 = *(const float4*)&L0o[3 * 256 + k0];
            float w0 = wp[(k0 + 0) * 128], w1 = wp[(k0 + 1) * 128];
            float w2 = wp[(k0 + 2) * 128], w3 = wp[(k0 + 3) * 128];
            acc[0] = fmaf(x0.x, w0, acc[0]); acc[0] = fmaf(x0.y, w1, acc[0]);
            acc[0] = fmaf(x0.z, w2, acc[0]); acc[0] = fmaf(x0.w, w3, acc[0]);
            acc[1] = fmaf(x1.x, w0, acc[1]); acc[1] = fmaf(x1.y, w1, acc[1]);
            acc[1] = fmaf(x1.z, w2, acc[1]); acc[1] = fmaf(x1.w, w3, acc[1]);
            acc[2] = fmaf(x2.x, w0, acc[2]); acc[2] = fmaf(x2.y, w1, acc[2]);
            acc[2] = fmaf(x2.z, w2, acc[2]); acc[2] = fmaf(x2.w, w3, acc[2]);
            acc[3] = fmaf(x3.x, w0, acc[3]); acc[3] = fmaf(x3.y, w1, acc[3]);
            acc[3] = fmaf(x3.z, w2, acc[3]); acc[3] = fmaf(x3.w, w3, acc[3]);
        }
        float bb = B1[co];
        #pragma unroll
        for (int p = 0; p < 4; ++p) {
            int i = p >> 1, j = p & 1;
            L1o[((2 * i + di) * 4 + 2 * j + dj) * 128 + co] = fmaxf(acc[p] + bb, 0.f);
        }
    }
    __syncthreads();

    // ---- L2: K=128 -> 64co, 4x4 -> 8x8. wave = (tap, px-half); lane = co.
    {
        const int co = lane;
        const int t = wv & 3, ih = wv >> 2;
        const int ft = 3 - t, di = t >> 1, dj = t & 1;
        const float* wp = W2 + (size_t)ft * 128 * 64 + co;
        float acc[8] = {0.f,0.f,0.f,0.f,0.f,0.f,0.f,0.f};
        #pragma unroll 2
        for (int q = 0; q < 32; ++q) {
            int k0 = q * 4;
            float w0 = wp[(k0 + 0) * 64], w1 = wp[(k0 + 1) * 64];
            float w2 = wp[(k0 + 2) * 64], w3 = wp[(k0 + 3) * 64];
            #pragma unroll
            for (int pp = 0; pp < 8; ++pp) {
                float4 xq = *(const float4*)&L1o[(ih * 8 + pp) * 128 + k0];
                acc[pp] = fmaf(xq.x, w0, acc[pp]);
                acc[pp] = fmaf(xq.y, w1, acc[pp]);
                acc[pp] = fmaf(xq.z, w2, acc[pp]);
                acc[pp] = fmaf(xq.w, w3, acc[pp]);
            }
        }
        float bb = B2[co];
        #pragma unroll
        for (int pp = 0; pp < 8; ++pp) {
            int p = ih * 8 + pp;
            int i = p >> 2, j = p & 3;
            int op = (2 * i + di) * 8 + 2 * j + dj;
            L2o[co * 66 + op] = fmaxf(acc[pp] + bb, 0.f);
        }
    }
    __syncthreads();

    // ---- L3: K=64 -> 32co, 8x8 -> 16x16. wave = (di, co-quarter); lane = px.
    {
        const int di = wv >> 2, coq = wv & 3;
        const int ft0 = 3 - 2 * di, ft1 = 2 - 2 * di;   // dj = 0 / 1
        const float* w0b = W3 + (size_t)ft0 * 64 * 32 + coq * 8;
        const float* w1b = W3 + (size_t)ft1 * 64 * 32 + coq * 8;
        float a0[8], a1[8];
        #pragma unroll
        for (int c = 0; c < 8; ++c) { a0[c] = 0.f; a1[c] = 0.f; }
        #pragma unroll 4
        for (int k = 0; k < 64; ++k) {
            float xv = L2o[k * 66 + lane];
            const float* w0p = w0b + k * 32;
            const float* w1p = w1b + k * 32;
            #pragma unroll
            for (int c = 0; c < 8; ++c) {
                a0[c] = fmaf(xv, w0p[c], a0[c]);
                a1[c] = fmaf(xv, w1p[c], a1[c]);
            }
        }
        int i = lane >> 3, j = lane & 7;
        #pragma unroll
        for (int c = 0; c < 8; ++c) {
            float bb = B3[coq * 8 + c];
            float2 v = make_float2(fmaxf(a0[c] + bb, 0.f), fmaxf(a1[c] + bb, 0.f));
            *(float2*)&L3o[(coq * 8 + c) * 256 + (2 * i + di) * 16 + 2 * j] = v;
        }
    }
    __syncthreads();

    // ---- L4 (K=32 -> 16co, 16x16 -> 32x32) + L5 (K=16 -> 3, sigmoid), 4 chunks.
    const int t5 = wv & 3, pxh5 = wv >> 2;
    const int ft5 = 3 - t5, di5 = t5 >> 1, dj5 = t5 & 1;
    float w5r[16][3];
    #pragma unroll
    for (int k = 0; k < 16; ++k)
        #pragma unroll
        for (int c = 0; c < 3; ++c)
            w5r[k][c] = W5[(ft5 * 16 + k) * 3 + c];
    const float b50 = B5[0], b51 = B5[1], b52 = B5[2];

    for (int c4 = 0; c4 < 4; ++c4) {
        {   // L4 on input rows 4c4..4c4+3. wave = (di, co-quarter); lane = px.
            const int di4 = wv >> 2, coq4 = wv & 3;
            const int ft0 = 3 - 2 * di4, ft1 = 2 - 2 * di4;
            const float* w0b = W4 + (size_t)ft0 * 32 * 16 + coq4 * 4;
            const float* w1b = W4 + (size_t)ft1 * 32 * 16 + coq4 * 4;
            float a0[4], a1[4];
            #pragma unroll
            for (int c = 0; c < 4; ++c) { a0[c] = 0.f; a1[c] = 0.f; }
            #pragma unroll 4
            for (int k = 0; k < 32; ++k) {
                float xv = L3o[k * 256 + 64 * c4 + lane];
                const float* w0p = w0b + k * 16;
                const float* w1p = w1b + k * 16;
                #pragma unroll
                for (int c = 0; c < 4; ++c) {
                    a0[c] = fmaf(xv, w0p[c], a0[c]);
                    a1[c] = fmaf(xv, w1p[c], a1[c]);
                }
            }
            int il = lane >> 4, j = lane & 15;
            #pragma unroll
            for (int c = 0; c < 4; ++c) {
                float bb = B4[coq4 * 4 + c];
                float2 v = make_float2(fmaxf(a0[c] + bb, 0.f), fmaxf(a1[c] + bb, 0.f));
                *(float2*)&L4b[(coq4 * 4 + c) * 258 + (2 * il + di4) * 32 + 2 * j] = v;
            }
        }
        __syncthreads();
        {   // L5: wave = (tap, px-half); 2 sub-rounds of 64 px.
            #pragma unroll
            for (int sub = 0; sub < 2; ++sub) {
                int pl = pxh5 * 128 + sub * 64 + lane;
                int r = pl >> 5, x5 = pl & 31;
                int y5 = 8 * c4 + r;
                float a0 = b50, a1 = b51, a2 = b52;
                #pragma unroll   // FULL unroll required: w5r[k] must be static-indexed
                for (int k = 0; k < 16; ++k) {
                    float xv = L4b[k * 258 + pl];
                    a0 = fmaf(xv, w5r[k][0], a0);
                    a1 = fmaf(xv, w5r[k][1], a1);
                    a2 = fmaf(xv, w5r[k][2], a2);
                }
                a0 = 1.0f / (1.0f + expf(-a0));
                a1 = 1.0f / (1.0f + expf(-a1));
                a2 = 1.0f / (1.0f + expf(-a2));
                // 4-channel padded dec: ONE b128 store per pixel
                float* dp = dec + (size_t)inst * 16384
                          + (size_t)((2 * y5 + di5) * 64 + 2 * x5 + dj5) * 4;
                *(float4*)dp = make_float4(a0, a1, a2, 0.f);
            }
        }
        __syncthreads();
    }
}

// Fused STN bilinear sample + weighted composite + in-block reduce.
// R11 composite structure; dec now (64,64,4) padded -> each bilinear corner
// is ONE float4 load (was 3 scalar loads): 12 -> 4 loads per box-pixel.
__global__ __launch_bounds__(1024) void composite_k(
    const float* __restrict__ dec, const float* __restrict__ wgt,
    const float* __restrict__ sxs, const float* __restrict__ oxs,
    const float* __restrict__ sys, const float* __restrict__ oys,
    const int* __restrict__ binst, const int* __restrict__ rect,
    const int* __restrict__ cidx, const int* __restrict__ cnt,
    float* __restrict__ out)
{
    __shared__ float pls[8][128][3];   // 12 KB

    int b = blockIdx.x >> 7, tile = blockIdx.x & 127;      // 8 x-tiles x 16 y-tiles
    int tx0 = (tile & 7) << 4, ty0 = (tile >> 3) << 3;     // 16 wide x 8 tall
    int s = threadIdx.x >> 7, px = threadIdx.x & 127;
    int lx = px & 15, ly = px >> 4;                        // 16 x 8
    int w = tx0 + lx, h = ty0 + ly;

    int nb = cnt[b];
    int lo = (nb * s) >> 3, hi = (nb * (s + 1)) >> 3;

    float fw = (float)w, fh = (float)h;
    float a0 = 0.f, a1 = 0.f, a2 = 0.f;
    for (int q = lo; q < hi; ++q) {
        int n = cidx[b * NBOX + q];
        int rc = rect[b * NBOX + n];
        int wlo = rc & 255, whi = (rc >> 8) & 255;
        int hlo = (rc >> 16) & 255, hhi = (rc >> 24) & 255;
        if (whi < tx0 || wlo > tx0 + 15 || hhi < ty0 || hlo > ty0 + 7) continue;
        int g = b * NBOX + n;
        float wg = wgt[g];
        float pxx = fmaf(fw, sxs[g], oxs[g]);
        float pyy = fmaf(fh, sys[g], oys[g]);
        float x0 = floorf(pxx), y0 = floorf(pyy);
        if (x0 < -1.0f || x0 > 63.0f || y0 < -1.0f || y0 > 63.0f) continue;
        float wx = pxx - x0, wy = pyy - y0;
        int ix = (int)x0, iy = (int)y0;
        int x0c = max(ix, 0), x1c = min(ix + 1, 63);
        int y0c = max(iy, 0), y1c = min(iy + 1, 63);
        float m00 = (ix >= 0 && iy >= 0) ? 1.f : 0.f;
        float m01 = (ix + 1 <= 63 && iy >= 0) ? 1.f : 0.f;
        float m10 = (ix >= 0 && iy + 1 <= 63) ? 1.f : 0.f;
        float m11 = (ix + 1 <= 63 && iy + 1 <= 63) ? 1.f : 0.f;
        float w00 = (1.f - wy) * (1.f - wx) * m00;
        float w01 = (1.f - wy) * wx * m01;
        float w10 = wy * (1.f - wx) * m10;
        float w11 = wy * wx * m11;
        const float* img = dec + (size_t)binst[g] * 16384;   // (64,64,4) HWC4
        float4 v00 = *(const float4*)&img[(y0c * 64 + x0c) * 4];
        float4 v01 = *(const float4*)&img[(y0c * 64 + x1c) * 4];
        float4 v10 = *(const float4*)&img[(y1c * 64 + x0c) * 4];
        float4 v11 = *(const float4*)&img[(y1c * 64 + x1c) * 4];
        a0 += wg * (w00 * v00.x + w01 * v01.x + w10 * v10.x + w11 * v11.x);
        a1 += wg * (w00 * v00.y + w01 * v01.y + w10 * v10.y + w11 * v11.y);
        a2 += wg * (w00 * v00.z + w01 * v01.z + w10 * v10.z + w11 * v11.z);
    }
    pls[s][px][0] = a0; pls[s][px][1] = a1; pls[s][px][2] = a2;
    __syncthreads();

    if (threadIdx.x < 384) {
        int c = threadIdx.x >> 7, p2 = threadIdx.x & 127;
        float v = 0.f;
        #pragma unroll
        for (int t = 0; t < 8; ++t) v += pls[t][p2][c];
        int h2 = ty0 + (p2 >> 4), w2 = tx0 + (p2 & 15);
        out[((b * 3 + c) * 128 + h2) * 128 + w2] = v;
    }
}

extern "C" void kernel_launch(void* const* d_in, const int* in_sizes, int n_in,
                              void* d_out, int out_size, void* d_ws, size_t ws_size,
                              hipStream_t stream)
{
    const float* z_what    = (const float*)d_in[0];   // (4,85,64)
    const float* z_where   = (const float*)d_in[1];   // (4,380,4)
    const int*   z_present = (const int*)  d_in[2];   // (4,380,1)
    const float* z_depth   = (const float*)d_in[3];   // (4,85,1)

    // workspace: dec (4-ch padded) 22.28 MB | params ~55 KB
    char* ws = (char*)d_ws;
    float* dec = (float*)ws;                           // 340*16384 f32
    float* P   = (float*)(ws + 22282240);
    float* wgt = P,        *sxs = P + 1520, *oxs = P + 2 * 1520;
    float* sys = P + 3 * 1520, *oys = P + 4 * 1520;
    int* binst = (int*)(P + 5 * 1520);
    int* rect  = binst + 1520;
    int* cidx  = binst + 2 * 1520;
    int* cnt   = binst + 3 * 1520;

    decode_fused_k<<<dim3(NINST + 4), dim3(512), 0, stream>>>(
        z_what,
        (const float*)d_in[4],  (const float*)d_in[5],
        (const float*)d_in[6],  (const float*)d_in[7],
        (const float*)d_in[8],  (const float*)d_in[9],
        (const float*)d_in[10], (const float*)d_in[11],
        (const float*)d_in[12], (const float*)d_in[13],
        (const float*)d_in[14], (const float*)d_in[15],
        z_where, z_present, z_depth,
        wgt, sxs, oxs, sys, oys, binst, rect, cidx, cnt,
        dec);

    composite_k<<<dim3(512), dim3(1024), 0, stream>>>(
        dec, wgt, sxs, oxs, sys, oys, binst, rect, cidx, cnt, (float*)d_out);
}